// Round 1
// baseline (3832.626 us; speedup 1.0000x reference)
//
#include <hip/hip_runtime.h>
#include <hip/hip_bf16.h>

#define VOCAB  32000
#define EMBED  512
#define HIDDEN 1024
#define BATCH  16
#define SEQ    256
#define NROW   (BATCH*SEQ)   // 4096 GEMM rows, r = s*16 + b
#define GCOLS  (4*HIDDEN)    // 4096 gate columns, col = g*1024 + j

typedef unsigned short u16;
typedef unsigned int   u32;
typedef __attribute__((ext_vector_type(4))) float f32x4;
typedef __attribute__((ext_vector_type(8))) short bf16x8;
typedef __attribute__((ext_vector_type(8))) unsigned short u16x8;

__device__ inline u16 f2bf(float f){
  __hip_bfloat16 h = __float2bfloat16(f);
  return __builtin_bit_cast(u16, h);
}

__device__ inline void gload_lds16(const void* g, void* l){
  __builtin_amdgcn_global_load_lds((const __attribute__((address_space(1))) u32*)g,
                                   (__attribute__((address_space(3))) u32*)l, 16, 0, 0);
}

// ---------------------------------------------------------------------------
// Pack weights into MFMA B-fragment order: Bp[nblk][kb][lane][e] (ushort bf16)
//   col = nblk*16 + (lane&15), k = kb*32 + (lane>>4)*8 + e
// Wxp : K=512  (rows 0..511 of W_g),  N=4096 (col = g*1024+j)
// Whp : K=1024 (rows 512..1535),      N=4096
// Woutp: K=1024 (W_out rows),         N=32000
// bcat : concatenated gate biases [4096]
// ---------------------------------------------------------------------------
__global__ __launch_bounds__(256) void pack_kernel(
    const float* __restrict__ Wf, const float* __restrict__ Wi,
    const float* __restrict__ Wc, const float* __restrict__ Wo,
    const float* __restrict__ Wout,
    const float* __restrict__ bf_, const float* __restrict__ bi_,
    const float* __restrict__ bc_, const float* __restrict__ bo_,
    u16* __restrict__ Wxp, u16* __restrict__ Whp, u16* __restrict__ Woutp,
    float* __restrict__ bcat)
{
  const int NT_WX   = (GCOLS/16)*(EMBED/32)*64;   // 262144
  const int NT_WH   = (GCOLS/16)*(HIDDEN/32)*64;  // 524288
  const int NT_WOUT = (VOCAB/16)*(HIDDEN/32)*64;  // 4096000
  int t = blockIdx.x*256 + threadIdx.x;
  if (t < NT_WX){
    int u = t;
    int lane = u&63; int kb = (u>>6)&15; int nblk = u>>10;
    int col = nblk*16 + (lane&15);
    int k0  = kb*32 + ((lane>>4)<<3);
    int g = col>>10, j = col&1023;
    const float* W = (g==0)?Wf:(g==1)?Wi:(g==2)?Wc:Wo;
    u16x8 v;
    #pragma unroll
    for (int e=0;e<8;e++) v[e] = f2bf(W[(size_t)(k0+e)*HIDDEN + j]);
    *(u16x8*)(Wxp + (size_t)u*8) = v;
  } else if (t < NT_WX + NT_WH){
    int u = t - NT_WX;
    int lane = u&63; int kb = (u>>6)&31; int nblk = u>>11;
    int col = nblk*16 + (lane&15);
    int k0  = kb*32 + ((lane>>4)<<3);
    int g = col>>10, j = col&1023;
    const float* W = (g==0)?Wf:(g==1)?Wi:(g==2)?Wc:Wo;
    u16x8 v;
    #pragma unroll
    for (int e=0;e<8;e++) v[e] = f2bf(W[(size_t)(EMBED + k0+e)*HIDDEN + j]);
    *(u16x8*)(Whp + (size_t)u*8) = v;
  } else if (t < NT_WX + NT_WH + NT_WOUT){
    int u = t - NT_WX - NT_WH;
    int lane = u&63; int kb = (u>>6)&31; int nblk = u>>11;
    int col = nblk*16 + (lane&15);
    int k0  = kb*32 + ((lane>>4)<<3);
    u16x8 v;
    #pragma unroll
    for (int e=0;e<8;e++) v[e] = f2bf(Wout[(size_t)(k0+e)*VOCAB + col]);
    *(u16x8*)(Woutp + (size_t)u*8) = v;
  } else {
    int u = t - NT_WX - NT_WH - NT_WOUT;
    if (u < GCOLS){
      int g = u>>10, j = u&1023;
      const float* B = (g==0)?bf_:(g==1)?bi_:(g==2)?bc_:bo_;
      bcat[u] = B[j];
    }
  }
}

// ---------------------------------------------------------------------------
// Embedding gather into MFMA A-fragment order: Ap[mblk][kb][lane][e]
//   row r = mblk*16+(lane&15) = s*16+b  (so mblk = s, lane&15 = b)
//   k = kb*32 + (lane>>4)*8 + e  (embedding dim)
// ---------------------------------------------------------------------------
__global__ __launch_bounds__(256) void gather_kernel(
    const int* __restrict__ tok, const float* __restrict__ embed, u16* __restrict__ Xg)
{
  int t = blockIdx.x*256 + threadIdx.x;   // 262144 total
  int lane = t&63; int kb = (t>>6)&15; int mblk = t>>10;
  int s = mblk; int b = lane&15;
  int token = tok[b*SEQ + s];
  int k0 = kb*32 + ((lane>>4)<<3);
  const float* src = embed + (size_t)token*EMBED + k0;
  u16x8 v;
  #pragma unroll
  for (int e=0;e<8;e++) v[e] = f2bf(src[e]);
  *(u16x8*)(Xg + (size_t)t*8) = v;
}

// ---------------------------------------------------------------------------
// 128x128 bf16 GEMM, packed-fragment A and B, m97 2-barrier structure.
// C[row][col] f32 = sum_k A[row][k]*B[k][col] + bias[col]
// REMAP: row r = s*16+b -> output row b*SEQ+s  (for the logits GEMM)
// ---------------------------------------------------------------------------
template<int KB, bool REMAP>
__global__ __launch_bounds__(256,2) void gemm_pk(
    const u16* __restrict__ Ap, const u16* __restrict__ Bp,
    const float* __restrict__ bias, float* __restrict__ C,
    int Nblk128, int N)
{
  __shared__ u16 sm[8192];   // A chunks [0,4096), B chunks [4096,8192)
  int tid = threadIdx.x; int lane = tid&63; int wv = tid>>6;
  int nwg = gridDim.x;
  int bid = blockIdx.x;
  int swz = (bid&7)*(nwg>>3) + (bid>>3);   // XCD-aware, bijective (nwg%8==0)
  int bm = swz / Nblk128, bn = swz % Nblk128;
  int wr = wv>>1, wc = wv&1;
  f32x4 acc[4][4] = {};
  const u16* Abase = Ap + (size_t)(bm*8)*KB*512;
  const u16* Bbase = Bp + (size_t)(bn*8)*KB*512;
  for (int kb=0; kb<KB; ++kb){
    __syncthreads();
    #pragma unroll
    for (int c2=0;c2<4;c2++){
      int chunk = wv*4 + c2;
      const u16* g;
      if (chunk < 8) g = Abase + ((size_t)chunk*KB + kb)*512 + lane*8;
      else           g = Bbase + ((size_t)(chunk-8)*KB + kb)*512 + lane*8;
      gload_lds16(g, sm + chunk*512);
    }
    __syncthreads();
    bf16x8 a[4], b[4];
    #pragma unroll
    for (int m=0;m<4;m++) a[m] = *(const bf16x8*)(sm + (wr*4+m)*512 + lane*8);
    #pragma unroll
    for (int n=0;n<4;n++) b[n] = *(const bf16x8*)(sm + 4096 + (wc*4+n)*512 + lane*8);
    #pragma unroll
    for (int m=0;m<4;m++)
      #pragma unroll
      for (int n=0;n<4;n++)
        acc[m][n] = __builtin_amdgcn_mfma_f32_16x16x32_bf16(a[m], b[n], acc[m][n], 0,0,0);
  }
  int colb = bn*128 + wc*64;
  int rowb = bm*128 + wr*64;
  #pragma unroll
  for (int m=0;m<4;m++){
    int row0 = rowb + m*16 + (lane>>4)*4;
    #pragma unroll
    for (int n=0;n<4;n++){
      int col = colb + n*16 + (lane&15);
      float bv = bias[col];
      #pragma unroll
      for (int r2=0;r2<4;r2++){
        int row = row0 + r2;
        int orow = REMAP ? ((row&15)*SEQ + (row>>4)) : row;
        C[(size_t)orow*N + col] = acc[m][n][r2] + bv;
      }
    }
  }
}

// ---------------------------------------------------------------------------
// LSTM recurrence. 64 WGs x 256 threads (4 waves). WG w owns hidden j in
// [w*16, w*16+16); wave g computes gate g via 32 chained 16x16x32 MFMAs with
// its Wh fragment slice preloaded in registers (nblk = g*64 + w of Whp).
// h double-buffered in global (bf16), per-step device-scope flag barrier.
// Writes Hp (A-fragment-packed hiddens) for the output GEMM.
// ---------------------------------------------------------------------------
__global__ __launch_bounds__(256,1) void lstm_rec(
    const u16* __restrict__ Whp, const float* __restrict__ Xpre,
    u16* hbufs, u16* __restrict__ Hp, u32* flags)
{
  int tid = threadIdx.x; int lane = tid&63; int g = tid>>6;
  int w = blockIdx.x;               // 0..63
  int nblk = g*64 + w;
  bf16x8 wf[32];
  const u16* wp = Whp + (size_t)nblk*32*512;
  #pragma unroll
  for (int kc=0;kc<32;kc++) wf[kc] = *(const bf16x8*)(wp + (size_t)kc*512 + lane*8);
  __shared__ float gl[4][16][17];
  __shared__ u16 hl[16][16];
  float c = 0.f;
  int pb = tid>>4, pj = tid&15;     // pointwise (batch, local j)
  int j = w*16 + pj;
  size_t hp_base = (size_t)(j>>5)*512 + (size_t)(((j>>3)&3)*16 + pb)*8 + (j&7);
  const int a_row = lane&15, a_k = (lane>>4)*8;
  for (int s=0;s<SEQ;s++){
    const u16* rbuf = hbufs + (s&1)*16384;       // holds h_{s-1}
    u16* wbuf = hbufs + ((s+1)&1)*16384;         // receives h_s
    f32x4 acc = {0.f,0.f,0.f,0.f};
    #pragma unroll
    for (int kc=0;kc<32;kc++){
      bf16x8 a = *(const bf16x8*)(rbuf + a_row*1024 + kc*32 + a_k);
      acc = __builtin_amdgcn_mfma_f32_16x16x32_bf16(a, wf[kc], acc, 0,0,0);
    }
    {
      int jj = lane&15, b0 = (lane>>4)*4;
      #pragma unroll
      for (int r2=0;r2<4;r2++) gl[g][b0+r2][jj] = acc[r2];
    }
    __syncthreads();
    const float* xp = Xpre + ((size_t)s*16 + pb)*GCOLS + j;
    float p0 = gl[0][pb][pj] + xp[0];
    float p1 = gl[1][pb][pj] + xp[1024];
    float p2 = gl[2][pb][pj] + xp[2048];
    float p3 = gl[3][pb][pj] + xp[3072];
    float fg = 1.f/(1.f+__expf(-p0));
    float ig = 1.f/(1.f+__expf(-p1));
    float e2 = __expf(2.f*fminf(fmaxf(p2,-15.f),15.f));
    float cand = (e2-1.f)/(e2+1.f);
    float og = 1.f/(1.f+__expf(-p3));
    c = c*fg + cand*ig;
    float h = c*og;                  // reference: h = c * o (no tanh on c)
    u16 hb = f2bf(h);
    hl[pb][pj] = hb;
    Hp[(size_t)s*16384 + hp_base] = hb;
    __syncthreads();
    if (tid < 128){
      int b2 = tid>>3, q = tid&7;
      u32 val = ((u32)hl[b2][q*2+1]<<16) | (u32)hl[b2][q*2];
      __hip_atomic_store((u32*)wbuf + b2*512 + w*8 + q, val,
                         __ATOMIC_RELAXED, __HIP_MEMORY_SCOPE_AGENT);
    }
    __syncthreads();
    if (tid==0)
      __hip_atomic_store(flags + (size_t)w*16, (u32)(s+1),
                         __ATOMIC_RELEASE, __HIP_MEMORY_SCOPE_AGENT);
    if (g==0){
      u32 v;
      do {
        v = __hip_atomic_load(flags + (size_t)lane*16,
                              __ATOMIC_ACQUIRE, __HIP_MEMORY_SCOPE_AGENT);
        if (__all((int)v > s)) break;
        __builtin_amdgcn_s_sleep(1);
      } while (true);
    }
    __syncthreads();
    __threadfence();   // agent acquire: invalidate L1/L2 before reading new h
  }
}

// ---------------------------------------------------------------------------
extern "C" void kernel_launch(void* const* d_in, const int* in_sizes, int n_in,
                              void* d_out, int out_size, void* d_ws, size_t ws_size,
                              hipStream_t stream)
{
  (void)in_sizes; (void)n_in; (void)out_size; (void)ws_size;
  const int*   tok   = (const int*)d_in[0];
  const float* embed = (const float*)d_in[1];
  const float* Wf    = (const float*)d_in[2];
  const float* bf_   = (const float*)d_in[3];
  const float* Wi    = (const float*)d_in[4];
  const float* bi_   = (const float*)d_in[5];
  const float* Wc    = (const float*)d_in[6];
  const float* bc_   = (const float*)d_in[7];
  const float* Wo    = (const float*)d_in[8];
  const float* bo_   = (const float*)d_in[9];
  const float* Wout  = (const float*)d_in[10];
  const float* bout  = (const float*)d_in[11];
  float* out = (float*)d_out;

  char* ws = (char*)d_ws;
  size_t off = 0;
  auto alloc = [&](size_t bytes)->void*{
    void* p = ws + off; off += (bytes + 255) & ~(size_t)255; return p;
  };
  u16*  Wxp   = (u16*)alloc((size_t)2097152*2);
  u16*  Whp   = (u16*)alloc((size_t)4194304*2);
  u16*  Woutp = (u16*)alloc((size_t)32768000*2);
  float* bcat = (float*)alloc((size_t)4096*4);
  u16*  Xg    = (u16*)alloc((size_t)2097152*2);
  float* Xpre = (float*)alloc((size_t)NROW*GCOLS*4);   // 64 MB
  u16*  Hp    = (u16*)alloc((size_t)4194304*2);
  u16*  hbufs = (u16*)alloc((size_t)2*16384*2);        // 64 KB (two h buffers)
  u32*  flags = (u32*)alloc((size_t)4096);             // contiguous with hbufs

  hipMemsetAsync(hbufs, 0, 2*16384*2 + 4096, stream);

  pack_kernel<<<19088, 256, 0, stream>>>(Wf,Wi,Wc,Wo,Wout, bf_,bi_,bc_,bo_,
                                         Wxp, Whp, Woutp, bcat);
  gather_kernel<<<1024, 256, 0, stream>>>(tok, embed, Xg);
  gemm_pk<16,false><<<1024, 256, 0, stream>>>(Xg, Wxp, bcat, Xpre, 32, GCOLS);
  lstm_rec<<<64, 256, 0, stream>>>(Whp, Xpre, hbufs, Hp, flags);
  gemm_pk<32,true><<<8000, 256, 0, stream>>>(Hp, Woutp, bout, out, 250, VOCAB);
}

// Round 4
// 2291.083 us; speedup vs baseline: 1.6728x; 1.6728x over previous
//
#include <hip/hip_runtime.h>
#include <hip/hip_bf16.h>

#define VOCAB  32000
#define EMBED  512
#define HIDDEN 1024
#define BATCH  16
#define SEQ    256
#define NROW   (BATCH*SEQ)   // 4096 GEMM rows, r = s*16 + b
#define GCOLS  (4*HIDDEN)    // 4096 gate columns, col = g*1024 + j

typedef unsigned short u16;
typedef unsigned int   u32;
typedef unsigned long long u64;
typedef __attribute__((ext_vector_type(4))) float f32x4;
typedef __attribute__((ext_vector_type(8))) short bf16x8;
typedef __attribute__((ext_vector_type(8))) unsigned short u16x8;

__device__ inline u16 f2bf(float f){
  __hip_bfloat16 h = __float2bfloat16(f);
  return __builtin_bit_cast(u16, h);
}

__device__ inline void gload_lds16(const void* g, void* l){
  __builtin_amdgcn_global_load_lds((const __attribute__((address_space(1))) u32*)g,
                                   (__attribute__((address_space(3))) u32*)l, 16, 0, 0);
}

// ---------------------------------------------------------------------------
// Pack weights into MFMA B-fragment order: Bp[nblk][kb][lane][e] (ushort bf16)
//   col = nblk*16 + (lane&15), k = kb*32 + (lane>>4)*8 + e
// ---------------------------------------------------------------------------
__global__ __launch_bounds__(256) void pack_kernel(
    const float* __restrict__ Wf, const float* __restrict__ Wi,
    const float* __restrict__ Wc, const float* __restrict__ Wo,
    const float* __restrict__ Wout,
    const float* __restrict__ bf_, const float* __restrict__ bi_,
    const float* __restrict__ bc_, const float* __restrict__ bo_,
    u16* __restrict__ Wxp, u16* __restrict__ Whp, u16* __restrict__ Woutp,
    float* __restrict__ bcat)
{
  const int NT_WX   = (GCOLS/16)*(EMBED/32)*64;   // 262144
  const int NT_WH   = (GCOLS/16)*(HIDDEN/32)*64;  // 524288
  const int NT_WOUT = (VOCAB/16)*(HIDDEN/32)*64;  // 4096000
  int t = blockIdx.x*256 + threadIdx.x;
  if (t < NT_WX){
    int u = t;
    int lane = u&63; int kb = (u>>6)&15; int nblk = u>>10;
    int col = nblk*16 + (lane&15);
    int k0  = kb*32 + ((lane>>4)<<3);
    int g = col>>10, j = col&1023;
    const float* W = (g==0)?Wf:(g==1)?Wi:(g==2)?Wc:Wo;
    u16x8 v;
    #pragma unroll
    for (int e=0;e<8;e++) v[e] = f2bf(W[(size_t)(k0+e)*HIDDEN + j]);
    *(u16x8*)(Wxp + (size_t)u*8) = v;
  } else if (t < NT_WX + NT_WH){
    int u = t - NT_WX;
    int lane = u&63; int kb = (u>>6)&31; int nblk = u>>11;
    int col = nblk*16 + (lane&15);
    int k0  = kb*32 + ((lane>>4)<<3);
    int g = col>>10, j = col&1023;
    const float* W = (g==0)?Wf:(g==1)?Wi:(g==2)?Wc:Wo;
    u16x8 v;
    #pragma unroll
    for (int e=0;e<8;e++) v[e] = f2bf(W[(size_t)(EMBED + k0+e)*HIDDEN + j]);
    *(u16x8*)(Whp + (size_t)u*8) = v;
  } else if (t < NT_WX + NT_WH + NT_WOUT){
    int u = t - NT_WX - NT_WH;
    int lane = u&63; int kb = (u>>6)&31; int nblk = u>>11;
    int col = nblk*16 + (lane&15);
    int k0  = kb*32 + ((lane>>4)<<3);
    u16x8 v;
    #pragma unroll
    for (int e=0;e<8;e++) v[e] = f2bf(Wout[(size_t)(k0+e)*VOCAB + col]);
    *(u16x8*)(Woutp + (size_t)u*8) = v;
  } else {
    int u = t - NT_WX - NT_WH - NT_WOUT;
    if (u < GCOLS){
      int g = u>>10, j = u&1023;
      const float* B = (g==0)?bf_:(g==1)?bi_:(g==2)?bc_:bo_;
      bcat[u] = B[j];
    }
  }
}

// ---------------------------------------------------------------------------
// Embedding gather into MFMA A-fragment order.
// ---------------------------------------------------------------------------
__global__ __launch_bounds__(256) void gather_kernel(
    const int* __restrict__ tok, const float* __restrict__ embed, u16* __restrict__ Xg)
{
  int t = blockIdx.x*256 + threadIdx.x;   // 262144 total
  int lane = t&63; int kb = (t>>6)&15; int mblk = t>>10;
  int s = mblk; int b = lane&15;
  int token = tok[b*SEQ + s];
  int k0 = kb*32 + ((lane>>4)<<3);
  const float* src = embed + (size_t)token*EMBED + k0;
  u16x8 v;
  #pragma unroll
  for (int e=0;e<8;e++) v[e] = f2bf(src[e]);
  *(u16x8*)(Xg + (size_t)t*8) = v;
}

// ---------------------------------------------------------------------------
// 128x128 bf16 GEMM, packed-fragment A and B, m97 2-barrier structure.
// ---------------------------------------------------------------------------
template<int KB, bool REMAP>
__global__ __launch_bounds__(256,2) void gemm_pk(
    const u16* __restrict__ Ap, const u16* __restrict__ Bp,
    const float* __restrict__ bias, float* __restrict__ C,
    int Nblk128, int N)
{
  __shared__ u16 sm[8192];   // A chunks [0,4096), B chunks [4096,8192)
  int tid = threadIdx.x; int lane = tid&63; int wv = tid>>6;
  int nwg = gridDim.x;
  int bid = blockIdx.x;
  int swz = (bid&7)*(nwg>>3) + (bid>>3);   // XCD-aware, bijective (nwg%8==0)
  int bm = swz / Nblk128, bn = swz % Nblk128;
  int wr = wv>>1, wc = wv&1;
  f32x4 acc[4][4] = {};
  const u16* Abase = Ap + (size_t)(bm*8)*KB*512;
  const u16* Bbase = Bp + (size_t)(bn*8)*KB*512;
  for (int kb=0; kb<KB; ++kb){
    __syncthreads();
    #pragma unroll
    for (int c2=0;c2<4;c2++){
      int chunk = wv*4 + c2;
      const u16* g;
      if (chunk < 8) g = Abase + ((size_t)chunk*KB + kb)*512 + lane*8;
      else           g = Bbase + ((size_t)(chunk-8)*KB + kb)*512 + lane*8;
      gload_lds16(g, sm + chunk*512);
    }
    __syncthreads();
    bf16x8 a[4], b[4];
    #pragma unroll
    for (int m=0;m<4;m++) a[m] = *(const bf16x8*)(sm + (wr*4+m)*512 + lane*8);
    #pragma unroll
    for (int n=0;n<4;n++) b[n] = *(const bf16x8*)(sm + 4096 + (wc*4+n)*512 + lane*8);
    #pragma unroll
    for (int m=0;m<4;m++)
      #pragma unroll
      for (int n=0;n<4;n++)
        acc[m][n] = __builtin_amdgcn_mfma_f32_16x16x32_bf16(a[m], b[n], acc[m][n], 0,0,0);
  }
  int colb = bn*128 + wc*64;
  int rowb = bm*128 + wr*64;
  #pragma unroll
  for (int m=0;m<4;m++){
    int row0 = rowb + m*16 + (lane>>4)*4;
    #pragma unroll
    for (int n=0;n<4;n++){
      int col = colb + n*16 + (lane&15);
      float bv = bias[col];
      #pragma unroll
      for (int r2=0;r2<4;r2++){
        int row = row0 + r2;
        int orow = REMAP ? ((row&15)*SEQ + (row>>4)) : row;
        C[(size_t)orow*N + col] = acc[m][n][r2] + bv;
      }
    }
  }
}

// ---------------------------------------------------------------------------
// LSTM recurrence, tightened handshake.
// 64 WGs x 256 threads (4 waves, 1 WG/CU, 1 wave/SIMD -> up to 512 VGPR).
// Per step: prefetch Xpre, preload ALL 32 A-frags (128 VGPR) from rbuf,
// 4-way-split MFMA chain, pointwise, 8B atomic h-stores (one wave instr),
// release flag, Hp store AFTER release, relaxed-spin + single acquire fence.
// ---------------------------------------------------------------------------
__global__ __launch_bounds__(256,1) void lstm_rec(
    const u16* __restrict__ Whp, const float* __restrict__ Xpre,
    u16* hbufs, u16* __restrict__ Hp, u32* flags)
{
  int tid = threadIdx.x; int lane = tid&63; int g = tid>>6;
  int w = blockIdx.x;               // 0..63
  bf16x8 wf[32];
  const u16* wp = Whp + (size_t)(g*64 + w)*32*512;
  #pragma unroll
  for (int kc=0;kc<32;kc++) wf[kc] = *(const bf16x8*)(wp + (size_t)kc*512 + lane*8);
  __shared__ float gl[4][16][17];
  __shared__ u16 hl[16][16];
  float c = 0.f;
  int pb = tid>>4, pj = tid&15;     // pointwise (batch, local j)
  int j = w*16 + pj;
  // u64 store geometry (tid<64): 4 consecutive j per thread
  int b2 = tid>>2, q = tid&3;
  int j0 = w*16 + q*4;
  size_t hp_u64 = ((size_t)(j0>>5)*512 + (size_t)((((j0&31)>>3)*16) + b2)*8 + (size_t)(j0&7)) >> 2;
  const int a_row = lane&15, a_k = (lane>>4)*8;
  for (int s=0;s<SEQ;s++){
    const u16* rbuf = hbufs + (s&1)*16384;       // holds h_{s-1}
    u16* wbuf = hbufs + ((s+1)&1)*16384;         // receives h_s
    // Xpre prefetch (independent of h) — issues early, consumed at pointwise
    const float* xp = Xpre + ((size_t)s*16 + pb)*GCOLS + j;
    float x0 = xp[0];
    float x1 = xp[1024];
    float x2 = xp[2048];
    float x3 = xp[3072];
    // preload all 32 A-fragments (independent loads, all in flight)
    bf16x8 af[32];
    #pragma unroll
    for (int kc=0;kc<32;kc++)
      af[kc] = *(const bf16x8*)(rbuf + a_row*1024 + kc*32 + a_k);
    f32x4 a0 = {0.f,0.f,0.f,0.f}, a1 = a0, a2 = a0, a3 = a0;
    #pragma unroll
    for (int kc=0;kc<32;kc+=4){
      a0 = __builtin_amdgcn_mfma_f32_16x16x32_bf16(af[kc+0], wf[kc+0], a0, 0,0,0);
      a1 = __builtin_amdgcn_mfma_f32_16x16x32_bf16(af[kc+1], wf[kc+1], a1, 0,0,0);
      a2 = __builtin_amdgcn_mfma_f32_16x16x32_bf16(af[kc+2], wf[kc+2], a2, 0,0,0);
      a3 = __builtin_amdgcn_mfma_f32_16x16x32_bf16(af[kc+3], wf[kc+3], a3, 0,0,0);
    }
    f32x4 acc = (a0 + a1) + (a2 + a3);
    {
      int jj = lane&15, b0 = (lane>>4)*4;
      #pragma unroll
      for (int r2=0;r2<4;r2++) gl[g][b0+r2][jj] = acc[r2];
    }
    __syncthreads();                               // B1
    float p0 = gl[0][pb][pj] + x0;
    float p1 = gl[1][pb][pj] + x1;
    float p2 = gl[2][pb][pj] + x2;
    float p3 = gl[3][pb][pj] + x3;
    float fg = 1.f/(1.f+__expf(-p0));
    float ig = 1.f/(1.f+__expf(-p1));
    float e2 = __expf(2.f*fminf(fmaxf(p2,-15.f),15.f));
    float cand = (e2-1.f)/(e2+1.f);
    float og = 1.f/(1.f+__expf(-p3));
    c = c*fg + cand*ig;
    float h = c*og;                  // reference: h = c * o (no tanh on c)
    hl[pb][pj] = f2bf(h);
    __syncthreads();                               // B2
    if (tid < 64){
      u64 val = *(const u64*)(&hl[b2][q*4]);
      if (s < SEQ-1){
        // h handshake data: 8B write-through stores (one wave instruction)
        __hip_atomic_store((u64*)wbuf + (size_t)b2*256 + w*4 + q, val,
                           __ATOMIC_RELAXED, __HIP_MEMORY_SCOPE_AGENT);
        if (tid == 0)
          __hip_atomic_store(flags + (size_t)w*32, (u32)(s+1),
                             __ATOMIC_RELEASE, __HIP_MEMORY_SCOPE_AGENT);
      }
      // Hp only read after kernel completes — keep out of handshake path
      // NOTE: one step = 16 batches x 1024 j = 16384 u16 = 4096 u64 (round-3 bug: was 2048)
      ((u64*)Hp)[(size_t)s*4096 + hp_u64] = val;
    }
    if (s < SEQ-1){
      if (g == 0){
        u32 tgt = (u32)(s+1);
        while (true){
          u32 v = __hip_atomic_load(flags + (size_t)lane*32,
                                    __ATOMIC_RELAXED, __HIP_MEMORY_SCOPE_AGENT);
          if (__all(v >= tgt)) break;
          __builtin_amdgcn_s_sleep(1);
        }
      }
      __syncthreads();                             // B3
      __builtin_amdgcn_fence(__ATOMIC_ACQUIRE, "agent");
    }
  }
}

// ---------------------------------------------------------------------------
extern "C" void kernel_launch(void* const* d_in, const int* in_sizes, int n_in,
                              void* d_out, int out_size, void* d_ws, size_t ws_size,
                              hipStream_t stream)
{
  (void)in_sizes; (void)n_in; (void)out_size; (void)ws_size;
  const int*   tok   = (const int*)d_in[0];
  const float* embed = (const float*)d_in[1];
  const float* Wf    = (const float*)d_in[2];
  const float* bf_   = (const float*)d_in[3];
  const float* Wi    = (const float*)d_in[4];
  const float* bi_   = (const float*)d_in[5];
  const float* Wc    = (const float*)d_in[6];
  const float* bc_   = (const float*)d_in[7];
  const float* Wo    = (const float*)d_in[8];
  const float* bo_   = (const float*)d_in[9];
  const float* Wout  = (const float*)d_in[10];
  const float* bout  = (const float*)d_in[11];
  float* out = (float*)d_out;

  char* ws = (char*)d_ws;
  size_t off = 0;
  auto alloc = [&](size_t bytes)->void*{
    void* p = ws + off; off += (bytes + 255) & ~(size_t)255; return p;
  };
  u16*  Wxp   = (u16*)alloc((size_t)2097152*2);
  u16*  Whp   = (u16*)alloc((size_t)4194304*2);
  u16*  Woutp = (u16*)alloc((size_t)32768000*2);
  float* bcat = (float*)alloc((size_t)4096*4);
  u16*  Xg    = (u16*)alloc((size_t)2097152*2);
  float* Xpre = (float*)alloc((size_t)NROW*GCOLS*4);   // 64 MB
  u16*  Hp    = (u16*)alloc((size_t)4194304*2);
  u16*  hbufs = (u16*)alloc((size_t)2*16384*2);        // 64 KB (two h buffers)
  u32*  flags = (u32*)alloc((size_t)64*128);           // 128B/flag line

  (void)hipMemsetAsync(hbufs, 0, 2*16384*2 + 64*128, stream);

  pack_kernel<<<19088, 256, 0, stream>>>(Wf,Wi,Wc,Wo,Wout, bf_,bi_,bc_,bo_,
                                         Wxp, Whp, Woutp, bcat);
  gather_kernel<<<1024, 256, 0, stream>>>(tok, embed, Xg);
  gemm_pk<16,false><<<1024, 256, 0, stream>>>(Xg, Wxp, bcat, Xpre, 32, GCOLS);
  lstm_rec<<<64, 256, 0, stream>>>(Whp, Xpre, hbufs, Hp, flags);
  gemm_pk<32,true><<<8000, 256, 0, stream>>>(Hp, Woutp, bout, out, 250, VOCAB);
}

// Round 5
// 2279.092 us; speedup vs baseline: 1.6816x; 1.0053x over previous
//
#include <hip/hip_runtime.h>
#include <hip/hip_bf16.h>

#define VOCAB  32000
#define EMBED  512
#define HIDDEN 1024
#define BATCH  16
#define SEQ    256
#define NROW   (BATCH*SEQ)   // 4096 GEMM rows, r = s*16 + b
#define GCOLS  (4*HIDDEN)    // 4096 gate columns, col = g*1024 + j

typedef unsigned short u16;
typedef unsigned int   u32;
typedef unsigned long long u64;
typedef __attribute__((ext_vector_type(4))) float f32x4;
typedef __attribute__((ext_vector_type(8))) short bf16x8;
typedef __attribute__((ext_vector_type(8))) unsigned short u16x8;

__device__ inline u16 f2bf(float f){
  __hip_bfloat16 h = __float2bfloat16(f);
  return __builtin_bit_cast(u16, h);
}

__device__ inline void gload_lds16(const void* g, void* l){
  __builtin_amdgcn_global_load_lds((const __attribute__((address_space(1))) u32*)g,
                                   (__attribute__((address_space(3))) u32*)l, 16, 0, 0);
}

// ---------------------------------------------------------------------------
// Pack weights into MFMA B-fragment order: Bp[nblk][kb][lane][e] (ushort bf16)
//   col = nblk*16 + (lane&15), k = kb*32 + (lane>>4)*8 + e
// ---------------------------------------------------------------------------
__global__ __launch_bounds__(256) void pack_kernel(
    const float* __restrict__ Wf, const float* __restrict__ Wi,
    const float* __restrict__ Wc, const float* __restrict__ Wo,
    const float* __restrict__ Wout,
    const float* __restrict__ bf_, const float* __restrict__ bi_,
    const float* __restrict__ bc_, const float* __restrict__ bo_,
    u16* __restrict__ Wxp, u16* __restrict__ Whp, u16* __restrict__ Woutp,
    float* __restrict__ bcat)
{
  const int NT_WX   = (GCOLS/16)*(EMBED/32)*64;   // 262144
  const int NT_WH   = (GCOLS/16)*(HIDDEN/32)*64;  // 524288
  const int NT_WOUT = (VOCAB/16)*(HIDDEN/32)*64;  // 4096000
  int t = blockIdx.x*256 + threadIdx.x;
  if (t < NT_WX){
    int u = t;
    int lane = u&63; int kb = (u>>6)&15; int nblk = u>>10;
    int col = nblk*16 + (lane&15);
    int k0  = kb*32 + ((lane>>4)<<3);
    int g = col>>10, j = col&1023;
    const float* W = (g==0)?Wf:(g==1)?Wi:(g==2)?Wc:Wo;
    u16x8 v;
    #pragma unroll
    for (int e=0;e<8;e++) v[e] = f2bf(W[(size_t)(k0+e)*HIDDEN + j]);
    *(u16x8*)(Wxp + (size_t)u*8) = v;
  } else if (t < NT_WX + NT_WH){
    int u = t - NT_WX;
    int lane = u&63; int kb = (u>>6)&31; int nblk = u>>11;
    int col = nblk*16 + (lane&15);
    int k0  = kb*32 + ((lane>>4)<<3);
    int g = col>>10, j = col&1023;
    const float* W = (g==0)?Wf:(g==1)?Wi:(g==2)?Wc:Wo;
    u16x8 v;
    #pragma unroll
    for (int e=0;e<8;e++) v[e] = f2bf(W[(size_t)(EMBED + k0+e)*HIDDEN + j]);
    *(u16x8*)(Whp + (size_t)u*8) = v;
  } else if (t < NT_WX + NT_WH + NT_WOUT){
    int u = t - NT_WX - NT_WH;
    int lane = u&63; int kb = (u>>6)&31; int nblk = u>>11;
    int col = nblk*16 + (lane&15);
    int k0  = kb*32 + ((lane>>4)<<3);
    u16x8 v;
    #pragma unroll
    for (int e=0;e<8;e++) v[e] = f2bf(Wout[(size_t)(k0+e)*VOCAB + col]);
    *(u16x8*)(Woutp + (size_t)u*8) = v;
  } else {
    int u = t - NT_WX - NT_WH - NT_WOUT;
    if (u < GCOLS){
      int g = u>>10, j = u&1023;
      const float* B = (g==0)?bf_:(g==1)?bi_:(g==2)?bc_:bo_;
      bcat[u] = B[j];
    }
  }
}

// ---------------------------------------------------------------------------
// Embedding gather into MFMA A-fragment order.
// ---------------------------------------------------------------------------
__global__ __launch_bounds__(256) void gather_kernel(
    const int* __restrict__ tok, const float* __restrict__ embed, u16* __restrict__ Xg)
{
  int t = blockIdx.x*256 + threadIdx.x;   // 262144 total
  int lane = t&63; int kb = (t>>6)&15; int mblk = t>>10;
  int s = mblk; int b = lane&15;
  int token = tok[b*SEQ + s];
  int k0 = kb*32 + ((lane>>4)<<3);
  const float* src = embed + (size_t)token*EMBED + k0;
  u16x8 v;
  #pragma unroll
  for (int e=0;e<8;e++) v[e] = f2bf(src[e]);
  *(u16x8*)(Xg + (size_t)t*8) = v;
}

// ---------------------------------------------------------------------------
// 128x128 bf16 GEMM, packed-fragment A and B, m97 2-barrier structure.
// ---------------------------------------------------------------------------
template<int KB, bool REMAP>
__global__ __launch_bounds__(256,2) void gemm_pk(
    const u16* __restrict__ Ap, const u16* __restrict__ Bp,
    const float* __restrict__ bias, float* __restrict__ C,
    int Nblk128, int N)
{
  __shared__ u16 sm[8192];   // A chunks [0,4096), B chunks [4096,8192)
  int tid = threadIdx.x; int lane = tid&63; int wv = tid>>6;
  int nwg = gridDim.x;
  int bid = blockIdx.x;
  int swz = (bid&7)*(nwg>>3) + (bid>>3);   // XCD-aware, bijective (nwg%8==0)
  int bm = swz / Nblk128, bn = swz % Nblk128;
  int wr = wv>>1, wc = wv&1;
  f32x4 acc[4][4] = {};
  const u16* Abase = Ap + (size_t)(bm*8)*KB*512;
  const u16* Bbase = Bp + (size_t)(bn*8)*KB*512;
  for (int kb=0; kb<KB; ++kb){
    __syncthreads();
    #pragma unroll
    for (int c2=0;c2<4;c2++){
      int chunk = wv*4 + c2;
      const u16* g;
      if (chunk < 8) g = Abase + ((size_t)chunk*KB + kb)*512 + lane*8;
      else           g = Bbase + ((size_t)(chunk-8)*KB + kb)*512 + lane*8;
      gload_lds16(g, sm + chunk*512);
    }
    __syncthreads();
    bf16x8 a[4], b[4];
    #pragma unroll
    for (int m=0;m<4;m++) a[m] = *(const bf16x8*)(sm + (wr*4+m)*512 + lane*8);
    #pragma unroll
    for (int n=0;n<4;n++) b[n] = *(const bf16x8*)(sm + 4096 + (wc*4+n)*512 + lane*8);
    #pragma unroll
    for (int m=0;m<4;m++)
      #pragma unroll
      for (int n=0;n<4;n++)
        acc[m][n] = __builtin_amdgcn_mfma_f32_16x16x32_bf16(a[m], b[n], acc[m][n], 0,0,0);
  }
  int colb = bn*128 + wc*64;
  int rowb = bm*128 + wr*64;
  #pragma unroll
  for (int m=0;m<4;m++){
    int row0 = rowb + m*16 + (lane>>4)*4;
    #pragma unroll
    for (int n=0;n<4;n++){
      int col = colb + n*16 + (lane&15);
      float bv = bias[col];
      #pragma unroll
      for (int r2=0;r2<4;r2++){
        int row = row0 + r2;
        int orow = REMAP ? ((row&15)*SEQ + (row>>4)) : row;
        C[(size_t)orow*N + col] = acc[m][n][r2] + bv;
      }
    }
  }
}

// ---------------------------------------------------------------------------
// LSTM recurrence. 64 WGs x 256 threads (4 waves, 1 WG/CU -> 512 VGPR budget).
// wf[32] (128 VGPR) PINNED via empty asm so the compiler cannot rematerialize
// the Wh loads inside the loop (the per-step acquire fence otherwise forces a
// 128KB/WG L2/L3 re-stream every step — the round-4 7.2us/step cost).
// ---------------------------------------------------------------------------
__global__ __launch_bounds__(256,1) void lstm_rec(
    const u16* __restrict__ Whp, const float* __restrict__ Xpre,
    u16* hbufs, u16* __restrict__ Hp, u32* flags)
{
  int tid = threadIdx.x; int lane = tid&63; int g = tid>>6;
  int w = blockIdx.x;               // 0..63
  bf16x8 wf[32];
  const u16* wp = Whp + (size_t)(g*64 + w)*32*512;
  #pragma unroll
  for (int kc=0;kc<32;kc++) wf[kc] = *(const bf16x8*)(wp + (size_t)kc*512 + lane*8);
  // Pin wf in VGPRs: the empty asm "redefines" each value, making reload from
  // Whp illegal -> 128 VGPRs stay live across the step loop (budget: 512).
  #pragma unroll
  for (int kc=0;kc<32;kc++) asm volatile("" : "+v"(wf[kc]));
  __shared__ float gl[4][16][17];
  __shared__ u16 hl[16][16];
  float c = 0.f;
  int pb = tid>>4, pj = tid&15;     // pointwise (batch, local j)
  int j = w*16 + pj;
  // u64 store geometry (tid<64): 4 consecutive j per thread
  int b2 = tid>>2, q = tid&3;
  int j0 = w*16 + q*4;
  size_t hp_u64 = ((size_t)(j0>>5)*512 + (size_t)((((j0&31)>>3)*16) + b2)*8 + (size_t)(j0&7)) >> 2;
  const int a_row = lane&15, a_k = (lane>>4)*8;
  for (int s=0;s<SEQ;s++){
    const u16* rbuf = hbufs + (s&1)*16384;       // holds h_{s-1}
    u16* wbuf = hbufs + ((s+1)&1)*16384;         // receives h_s
    // critical path first: all 32 A-fragments (independent, all in flight)
    bf16x8 af[32];
    #pragma unroll
    for (int kc=0;kc<32;kc++)
      af[kc] = *(const bf16x8*)(rbuf + a_row*1024 + kc*32 + a_k);
    // Xpre prefetch (independent of h) — consumed after B1
    const float* xp = Xpre + ((size_t)s*16 + pb)*GCOLS + j;
    float x0 = xp[0];
    float x1 = xp[1024];
    float x2 = xp[2048];
    float x3 = xp[3072];
    f32x4 a0 = {0.f,0.f,0.f,0.f}, a1 = a0, a2 = a0, a3 = a0;
    #pragma unroll
    for (int kc=0;kc<32;kc+=4){
      a0 = __builtin_amdgcn_mfma_f32_16x16x32_bf16(af[kc+0], wf[kc+0], a0, 0,0,0);
      a1 = __builtin_amdgcn_mfma_f32_16x16x32_bf16(af[kc+1], wf[kc+1], a1, 0,0,0);
      a2 = __builtin_amdgcn_mfma_f32_16x16x32_bf16(af[kc+2], wf[kc+2], a2, 0,0,0);
      a3 = __builtin_amdgcn_mfma_f32_16x16x32_bf16(af[kc+3], wf[kc+3], a3, 0,0,0);
    }
    f32x4 acc = (a0 + a1) + (a2 + a3);
    {
      int jj = lane&15, b0 = (lane>>4)*4;
      #pragma unroll
      for (int r2=0;r2<4;r2++) gl[g][b0+r2][jj] = acc[r2];
    }
    __syncthreads();                               // B1
    float p0 = gl[0][pb][pj] + x0;
    float p1 = gl[1][pb][pj] + x1;
    float p2 = gl[2][pb][pj] + x2;
    float p3 = gl[3][pb][pj] + x3;
    float fg = 1.f/(1.f+__expf(-p0));
    float ig = 1.f/(1.f+__expf(-p1));
    float e2 = __expf(2.f*fminf(fmaxf(p2,-15.f),15.f));
    float cand = (e2-1.f)/(e2+1.f);
    float og = 1.f/(1.f+__expf(-p3));
    c = c*fg + cand*ig;
    float h = c*og;                  // reference: h = c * o (no tanh on c)
    hl[pb][pj] = f2bf(h);
    __syncthreads();                               // B2
    if (tid < 64){
      u64 val = *(const u64*)(&hl[b2][q*4]);
      if (s < SEQ-1){
        // h handshake data: 8B write-through stores (one wave instruction)
        __hip_atomic_store((u64*)wbuf + (size_t)b2*256 + w*4 + q, val,
                           __ATOMIC_RELAXED, __HIP_MEMORY_SCOPE_AGENT);
        if (tid == 0)
          __hip_atomic_store(flags + (size_t)w*32, (u32)(s+1),
                             __ATOMIC_RELEASE, __HIP_MEMORY_SCOPE_AGENT);
      }
      // Hp only read after kernel completes — keep out of handshake path
      // one step = 16 batches x 1024 j = 16384 u16 = 4096 u64
      ((u64*)Hp)[(size_t)s*4096 + hp_u64] = val;
    }
    if (s < SEQ-1){
      if (g == 0){
        u32 tgt = (u32)(s+1);
        while (true){
          u32 v = __hip_atomic_load(flags + (size_t)lane*32,
                                    __ATOMIC_RELAXED, __HIP_MEMORY_SCOPE_AGENT);
          if (__all(v >= tgt)) break;
          __builtin_amdgcn_s_sleep(1);
        }
      }
      __syncthreads();                             // B3
      __builtin_amdgcn_fence(__ATOMIC_ACQUIRE, "agent");
    }
  }
}

// ---------------------------------------------------------------------------
extern "C" void kernel_launch(void* const* d_in, const int* in_sizes, int n_in,
                              void* d_out, int out_size, void* d_ws, size_t ws_size,
                              hipStream_t stream)
{
  (void)in_sizes; (void)n_in; (void)out_size; (void)ws_size;
  const int*   tok   = (const int*)d_in[0];
  const float* embed = (const float*)d_in[1];
  const float* Wf    = (const float*)d_in[2];
  const float* bf_   = (const float*)d_in[3];
  const float* Wi    = (const float*)d_in[4];
  const float* bi_   = (const float*)d_in[5];
  const float* Wc    = (const float*)d_in[6];
  const float* bc_   = (const float*)d_in[7];
  const float* Wo    = (const float*)d_in[8];
  const float* bo_   = (const float*)d_in[9];
  const float* Wout  = (const float*)d_in[10];
  const float* bout  = (const float*)d_in[11];
  float* out = (float*)d_out;

  char* ws = (char*)d_ws;
  size_t off = 0;
  auto alloc = [&](size_t bytes)->void*{
    void* p = ws + off; off += (bytes + 255) & ~(size_t)255; return p;
  };
  u16*  Wxp   = (u16*)alloc((size_t)2097152*2);
  u16*  Whp   = (u16*)alloc((size_t)4194304*2);
  u16*  Woutp = (u16*)alloc((size_t)32768000*2);
  float* bcat = (float*)alloc((size_t)4096*4);
  u16*  Xg    = (u16*)alloc((size_t)2097152*2);
  float* Xpre = (float*)alloc((size_t)NROW*GCOLS*4);   // 64 MB
  u16*  Hp    = (u16*)alloc((size_t)4194304*2);
  u16*  hbufs = (u16*)alloc((size_t)2*16384*2);        // 64 KB (two h buffers)
  u32*  flags = (u32*)alloc((size_t)64*128);           // 128B/flag line

  (void)hipMemsetAsync(hbufs, 0, 2*16384*2 + 64*128, stream);

  pack_kernel<<<19088, 256, 0, stream>>>(Wf,Wi,Wc,Wo,Wout, bf_,bi_,bc_,bo_,
                                         Wxp, Whp, Woutp, bcat);
  gather_kernel<<<1024, 256, 0, stream>>>(tok, embed, Xg);
  gemm_pk<16,false><<<1024, 256, 0, stream>>>(Xg, Wxp, bcat, Xpre, 32, GCOLS);
  lstm_rec<<<64, 256, 0, stream>>>(Whp, Xpre, hbufs, Hp, flags);
  gemm_pk<32,true><<<8000, 256, 0, stream>>>(Hp, Woutp, bout, out, 250, VOCAB);
}